// Round 2
// baseline (143.405 us; speedup 1.0000x reference)
//
#include <hip/hip_runtime.h>

typedef float f32x4 __attribute__((ext_vector_type(4)));
typedef _Float16 f16x8 __attribute__((ext_vector_type(8)));

#define OFF_W2H 0        /* 128 rows x 256B fp16 hi, XOR-swizzled        */
#define OFF_W2L 32768    /* 128 rows x 256B fp16 lo                      */
#define OFF_W1  65536    /* 128 rows x 64B packed hi/lo K-slots          */
#define OFF_W3H 73728    /* 16 rows x 256B hi (rows >=4 zero)            */
#define OFF_W3L 77824    /* 16 rows x 256B lo                            */
#define OFF_B1  81920    /* f32[128] */
#define OFF_B2  82432    /* f32[128] */
#define OFF_B3  82944    /* f32[4]   */
#define LDS_BYTES 82960

// Kahan-accurate 2x2 determinant (sign must match the f64 numpy reference's
// rotation-vs-reflection branch).
__device__ inline float kdet(float a, float b, float c, float d) {
    float w = b * c;
    float e = fmaf(b, c, -w);
    return fmaf(a, d, -w) - e;
}

// Orthogonal polar factor R of F=[[a,b],[c,d]] (== U@Vh of the SVD).
__device__ inline void polar2(float a, float b, float c, float d, float det,
                              float& R00, float& R01, float& R10, float& R11) {
    if (det >= 0.f) {
        float h1 = a + d, h2 = c - b;
        float q = fmaxf(sqrtf(h1 * h1 + h2 * h2), 1e-30f);
        float iq = 1.f / q;
        R00 = h1 * iq; R01 = -h2 * iq; R10 = h2 * iq; R11 = h1 * iq;
    } else {
        float h1 = a - d, h2 = b + c;
        float q = fmaxf(sqrtf(h1 * h1 + h2 * h2), 1e-30f);
        float iq = 1.f / q;
        R00 = h1 * iq; R01 = h2 * iq; R10 = h2 * iq; R11 = -h1 * iq;
    }
}

// Logical K-slot map used identically on A and B sides (permutation cancels
// inside MFMA): k(g,e) = 4g + (e&3) + 16*(e>>2).
// Hidden-channel map (absorbs C/D layout col=lane&15,row=4*(lane>>4)+reg):
// c(g,e,kb) = 32kb + 16*(e>>2) + 4g + (e&3).
__device__ inline void stage_weights(unsigned char* s, const float* w1, int D,
                                     const float* b1, const float* w2, const float* b2,
                                     const float* w3, const float* b3) {
    const int tid = threadIdx.x, nt = blockDim.x;
    for (int idx = tid; idx < 2048; idx += nt) {           // w2 hi+lo: (j,kb,g)
        int j = idx >> 4, kb = (idx >> 2) & 3, g = idx & 3;
        const float* src = w2 + j * 128 + kb * 32 + g * 4;
        f16x8 vh, vl;
        #pragma unroll
        for (int e = 0; e < 8; ++e) {
            float w = src[(e & 3) + 16 * (e >> 2)];
            _Float16 h = (_Float16)w;
            vh[e] = h;
            vl[e] = (_Float16)(w - (float)h);
        }
        int off = j * 256 + ((kb * 64 + g * 16) ^ ((j & 7) << 4));
        *(f16x8*)(s + OFF_W2H + off) = vh;
        *(f16x8*)(s + OFF_W2L + off) = vl;
    }
    // w1 packed split: logical k in [0,D): W_hi (pairs x_hi); [8,8+D): W_hi
    // (pairs x_lo); [16,16+D): W_lo (pairs x_hi). One MFMA does all 3 terms.
    for (int idx = tid; idx < 512; idx += nt) {            // (j,g)
        int j = idx >> 2, g = idx & 3;
        f16x8 v;
        #pragma unroll
        for (int e = 0; e < 8; ++e) {
            int k = 4 * g + (e & 3) + 16 * (e >> 2);
            _Float16 val = (_Float16)0.f;
            if (k < D) val = (_Float16)w1[j * D + k];
            else if (k >= 8 && k < 8 + D) val = (_Float16)w1[j * D + (k - 8)];
            else if (k >= 16 && k < 16 + D) {
                float w = w1[j * D + (k - 16)];
                val = (_Float16)(w - (float)(_Float16)w);
            }
            v[e] = val;
        }
        int gg = g ^ ((j ^ (j >> 2)) & 3);
        *(f16x8*)(s + OFF_W1 + j * 64 + gg * 16) = v;
    }
    for (int idx = tid; idx < 256; idx += nt) {            // w3 hi+lo, 16 rows
        int j = idx >> 4, kb = (idx >> 2) & 3, g = idx & 3;
        f16x8 vh, vl;
        #pragma unroll
        for (int e = 0; e < 8; ++e) {
            int c = 32 * kb + 4 * g + (e & 3) + 16 * (e >> 2);
            float w = (j < 4) ? w3[j * 128 + c] : 0.f;
            _Float16 h = (_Float16)w;
            vh[e] = h;
            vl[e] = (_Float16)(w - (float)h);
        }
        int off = j * 256 + ((kb * 64 + g * 16) ^ ((j & 7) << 4));
        *(f16x8*)(s + OFF_W3H + off) = vh;
        *(f16x8*)(s + OFF_W3L + off) = vl;
    }
    for (int idx = tid; idx < 128; idx += nt) {
        ((float*)(s + OFF_B1))[idx] = b1[idx];
        ((float*)(s + OFF_B2))[idx] = b2[idx];
    }
    if (tid < 4) ((float*)(s + OFF_B3))[tid] = b3[tid];
}

// Build the layer-1 B fragment from x[0..7] (zero-padded past D).
// Per the packed-k map: g0:{xh0..3,xh0..3} g1:{xh4..7,xh4..7}
//                       g2:{xl0..3,0..}    g3:{xl4..7,0..}
__device__ inline f16x8 build_b1(const float* xin, int g) {
    _Float16 xh[8], xl[8];
    #pragma unroll
    for (int c = 0; c < 8; ++c) {
        float v = xin[c];
        _Float16 h = (_Float16)v;
        xh[c] = h;
        xl[c] = (_Float16)(v - (float)h);
    }
    const _Float16 z = (_Float16)0.f;
    f16x8 b;
    if (g == 0) {
        b[0] = xh[0]; b[1] = xh[1]; b[2] = xh[2]; b[3] = xh[3];
        b[4] = xh[0]; b[5] = xh[1]; b[6] = xh[2]; b[7] = xh[3];
    } else if (g == 1) {
        b[0] = xh[4]; b[1] = xh[5]; b[2] = xh[6]; b[3] = xh[7];
        b[4] = xh[4]; b[5] = xh[5]; b[6] = xh[6]; b[7] = xh[7];
    } else if (g == 2) {
        b[0] = xl[0]; b[1] = xl[1]; b[2] = xl[2]; b[3] = xl[3];
        b[4] = z; b[5] = z; b[6] = z; b[7] = z;
    } else {
        b[0] = xl[4]; b[1] = xl[5]; b[2] = xl[6]; b[3] = xl[7];
        b[4] = z; b[5] = z; b[6] = z; b[7] = z;
    }
    return b;
}

// Split-fp16 MLP, f32-quality: each logical GEMM = Wh*xh + Wh*xl + Wl*xh.
__device__ inline void mlp128(const unsigned char* s, f16x8 b1f, int m, int g,
                              float xout[4]) {
    const f32x4 zero = {0.f, 0.f, 0.f, 0.f};
    f32x4 acc[8];
    #pragma unroll
    for (int mb = 0; mb < 8; ++mb) {                       // layer1: 8 MFMAs
        int row = m + 16 * mb;
        int gg = g ^ ((row ^ (row >> 2)) & 3);
        f16x8 af = *(const f16x8*)(s + OFF_W1 + row * 64 + gg * 16);
        acc[mb] = __builtin_amdgcn_mfma_f32_16x16x32_f16(af, b1f, zero, 0, 0, 0);
    }
    #pragma unroll
    for (int mb = 0; mb < 8; ++mb) {                       // +b1, relu
        f32x4 bq = *(const f32x4*)(s + OFF_B1 + (mb * 16 + g * 4) * 4);
        #pragma unroll
        for (int r = 0; r < 4; ++r) acc[mb][r] = fmaxf(acc[mb][r] + bq[r], 0.f);
    }
    f16x8 hh[4], hl[4];
    #pragma unroll
    for (int kb = 0; kb < 4; ++kb)                         // split repack
        #pragma unroll
        for (int e = 0; e < 8; ++e) {
            float v = acc[2 * kb + (e >> 2)][e & 3];
            _Float16 h = (_Float16)v;
            hh[kb][e] = h;
            hl[kb][e] = (_Float16)(v - (float)h);
        }
    f32x4 acc2[8];
    #pragma unroll
    for (int mb = 0; mb < 8; ++mb) acc2[mb] = zero;
    #pragma unroll
    for (int mb = 0; mb < 8; ++mb) {                       // layer2: 96 MFMAs
        int row = m + 16 * mb;
        #pragma unroll
        for (int kb = 0; kb < 4; ++kb) {
            int off = row * 256 + ((kb * 64 + g * 16) ^ ((row & 7) << 4));
            f16x8 ah = *(const f16x8*)(s + OFF_W2H + off);
            f16x8 al = *(const f16x8*)(s + OFF_W2L + off);
            acc2[mb] = __builtin_amdgcn_mfma_f32_16x16x32_f16(ah, hh[kb], acc2[mb], 0, 0, 0);
            acc2[mb] = __builtin_amdgcn_mfma_f32_16x16x32_f16(ah, hl[kb], acc2[mb], 0, 0, 0);
            acc2[mb] = __builtin_amdgcn_mfma_f32_16x16x32_f16(al, hh[kb], acc2[mb], 0, 0, 0);
        }
    }
    #pragma unroll
    for (int mb = 0; mb < 8; ++mb) {                       // +b2, relu
        f32x4 bq = *(const f32x4*)(s + OFF_B2 + (mb * 16 + g * 4) * 4);
        #pragma unroll
        for (int r = 0; r < 4; ++r) acc2[mb][r] = fmaxf(acc2[mb][r] + bq[r], 0.f);
    }
    f16x8 h2h[4], h2l[4];
    #pragma unroll
    for (int kb = 0; kb < 4; ++kb)
        #pragma unroll
        for (int e = 0; e < 8; ++e) {
            float v = acc2[2 * kb + (e >> 2)][e & 3];
            _Float16 h = (_Float16)v;
            h2h[kb][e] = h;
            h2l[kb][e] = (_Float16)(v - (float)h);
        }
    f32x4 acc3 = zero;
    #pragma unroll
    for (int kb = 0; kb < 4; ++kb) {                       // layer3: 12 MFMAs
        int off = m * 256 + ((kb * 64 + g * 16) ^ ((m & 7) << 4));
        f16x8 ah = *(const f16x8*)(s + OFF_W3H + off);
        f16x8 al = *(const f16x8*)(s + OFF_W3L + off);
        acc3 = __builtin_amdgcn_mfma_f32_16x16x32_f16(ah, h2h[kb], acc3, 0, 0, 0);
        acc3 = __builtin_amdgcn_mfma_f32_16x16x32_f16(ah, h2l[kb], acc3, 0, 0, 0);
        acc3 = __builtin_amdgcn_mfma_f32_16x16x32_f16(al, h2h[kb], acc3, 0, 0, 0);
    }
    f32x4 b3q = *(const f32x4*)(s + OFF_B3);
    #pragma unroll
    for (int o = 0; o < 4; ++o)                            // broadcast from g==0
        xout[o] = __shfl(acc3[o] + b3q[o], m, 64);
}

__global__ __launch_bounds__(512) void k_dc(const float* __restrict__ Fin,
    const float* __restrict__ w1, const float* __restrict__ b1,
    const float* __restrict__ w2, const float* __restrict__ b2,
    const float* __restrict__ w3, const float* __restrict__ b3,
    float* __restrict__ out, int nelem) {
    extern __shared__ unsigned char s[];
    stage_weights(s, w1, 7, b1, w2, b2, w3, b3);
    __syncthreads();
    const int lane = threadIdx.x & 63;
    const int m = lane & 15, g = lane >> 4;
    const int wid = blockIdx.x * (blockDim.x >> 6) + (threadIdx.x >> 6);
    const int nw = gridDim.x * (blockDim.x >> 6);
    const int niter = nelem >> 4;
    for (int it = wid; it < niter; it += nw) {
        const int elem = it * 16 + m;
        f32x4 f = ((const f32x4*)Fin)[elem];
        float a = f[0], b = f[1], c = f[2], d = f[3];
        float det = kdet(a, b, c, d);
        float R00, R01, R10, R11;
        polar2(a, b, c, d, det, R00, R01, R10, R11);
        float E = 0.5f * (a + d), Hh = 0.5f * (c - b);
        float Fv = 0.5f * (a - d), G = 0.5f * (b + c);
        float Q = sqrtf(E * E + Hh * Hh), Rr = sqrtf(Fv * Fv + G * G);
        float inv[8];
        inv[0] = Q + Rr - 1.f;                  // s1 - 1
        inv[1] = fabsf(Q - Rr) - 1.f;           // s2 - 1
        inv[2] = fmaf(a, a, c * c) - 1.f;       // F^T F - I
        inv[3] = fmaf(a, b, c * d);
        inv[4] = inv[3];
        inv[5] = fmaf(b, b, d * d) - 1.f;
        inv[6] = det - 1.f;
        inv[7] = 0.f;
        f16x8 b1f = build_b1(inv, g);
        float x[4];
        mlp128(s, b1f, m, g, x);
        float x01 = 0.5f * (x[1] + x[2]);       // symmetrize
        float Fp00 = fmaf(R00, x[0], fmaf(R01, x01, a));
        float Fp01 = fmaf(R00, x01, fmaf(R01, x[3], b));
        float Fp10 = fmaf(R10, x[0], fmaf(R11, x01, c));
        float Fp11 = fmaf(R10, x01, fmaf(R11, x[3], d));
        if (g == 0) {
            f32x4 r = {Fp00, Fp01, Fp10, Fp11};
            ((f32x4*)out)[elem] = r;            // stage Fp in d_out
        }
    }
}

__global__ __launch_bounds__(512) void k_sp(float* io,
    const float* __restrict__ w1, const float* __restrict__ b1,
    const float* __restrict__ w2, const float* __restrict__ b2,
    const float* __restrict__ w3, const float* __restrict__ b3, int nelem) {
    extern __shared__ unsigned char s[];
    stage_weights(s, w1, 3, b1, w2, b2, w3, b3);
    __syncthreads();
    const int lane = threadIdx.x & 63;
    const int m = lane & 15, g = lane >> 4;
    const int wid = blockIdx.x * (blockDim.x >> 6) + (threadIdx.x >> 6);
    const int nw = gridDim.x * (blockDim.x >> 6);
    const int niter = nelem >> 4;
    for (int it = wid; it < niter; it += nw) {
        const int elem = it * 16 + m;
        f32x4 fp = ((const f32x4*)io)[elem];    // Fp from k_dc
        float a = fp[0], b = fp[1], c = fp[2], d = fp[3];
        float det = kdet(a, b, c, d);
        float R00, R01, R10, R11;
        polar2(a, b, c, d, det, R00, R01, R10, R11);
        float E = 0.5f * (a + d), Hh = 0.5f * (c - b);
        float Fv = 0.5f * (a - d), G = 0.5f * (b + c);
        float Q = sqrtf(E * E + Hh * Hh), Rr = sqrtf(Fv * Fv + G * G);
        float inv[8];
        inv[0] = (Q + Rr) + fabsf(Q - Rr) - 2.f; // s1+s2-2
        inv[1] = fmaf(a, a, fmaf(b, b, fmaf(c, c, d * d))) - 1.f;
        inv[2] = det - 1.f;
        inv[3] = 0.f; inv[4] = 0.f; inv[5] = 0.f; inv[6] = 0.f; inv[7] = 0.f;
        f16x8 b1f = build_b1(inv, g);
        float y[4];
        mlp128(s, b1f, m, g, y);
        float y01 = 0.5f * (y[1] + y[2]);
        float P00 = fmaf(R00, y[0], R01 * y01);
        float P01 = fmaf(R00, y01, R01 * y[3]);
        float P10 = fmaf(R10, y[0], R11 * y01);
        float P11 = fmaf(R10, y01, R11 * y[3]);
        // cauchy = P @ Fp^T
        float C00 = fmaf(P00, a, P01 * b);
        float C01 = fmaf(P00, c, P01 * d);
        float C10 = fmaf(P10, a, P11 * b);
        float C11 = fmaf(P10, c, P11 * d);
        if (g == 0) {
            f32x4 r = {C00, C01, C10, C11};
            ((f32x4*)io)[elem] = r;
        }
    }
}

extern "C" void kernel_launch(void* const* d_in, const int* in_sizes, int n_in,
                              void* d_out, int out_size, void* d_ws, size_t ws_size,
                              hipStream_t stream) {
    const float* F     = (const float*)d_in[0];
    const float* dc_w1 = (const float*)d_in[1];
    const float* dc_b1 = (const float*)d_in[2];
    const float* dc_w2 = (const float*)d_in[3];
    const float* dc_b2 = (const float*)d_in[4];
    const float* dc_w3 = (const float*)d_in[5];
    const float* dc_b3 = (const float*)d_in[6];
    const float* sp_w1 = (const float*)d_in[7];
    const float* sp_b1 = (const float*)d_in[8];
    const float* sp_w2 = (const float*)d_in[9];
    const float* sp_b2 = (const float*)d_in[10];
    const float* sp_w3 = (const float*)d_in[11];
    const float* sp_b3 = (const float*)d_in[12];
    float* out = (float*)d_out;
    const int nelem = in_sizes[0] / 4;
    // >64KB dynamic LDS opt-in (host-side attr set; not a stream op, so
    // graph-capture-safe; idempotent).
    hipFuncSetAttribute((const void*)k_dc,
                        hipFuncAttributeMaxDynamicSharedMemorySize, LDS_BYTES);
    hipFuncSetAttribute((const void*)k_sp,
                        hipFuncAttributeMaxDynamicSharedMemorySize, LDS_BYTES);
    dim3 grid(256), block(512);
    k_dc<<<grid, block, LDS_BYTES, stream>>>(F, dc_w1, dc_b1, dc_w2, dc_b2,
                                             dc_w3, dc_b3, out, nelem);
    k_sp<<<grid, block, LDS_BYTES, stream>>>(out, sp_w1, sp_b1, sp_w2, sp_b2,
                                             sp_w3, sp_b3, nelem);
}

// Round 3
// 127.492 us; speedup vs baseline: 1.1248x; 1.1248x over previous
//
#include <hip/hip_runtime.h>

typedef float f32x4 __attribute__((ext_vector_type(4)));
typedef _Float16 f16x8 __attribute__((ext_vector_type(8)));

#define OFF_W2H 0        /* 128 rows x 256B fp16 hi, XOR-swizzled        */
#define OFF_W2L 32768    /* 128 rows x 256B fp16 lo                      */
#define OFF_W1  65536    /* 128 rows x 64B packed hi/lo K-slots          */
#define OFF_W3H 73728    /* 5 rows x 256B hi (row 4 = shared zero row)   */
#define OFF_W3L 75008    /* 5 rows x 256B lo                             */
#define OFF_B1  76288    /* f32[128] */
#define OFF_B2  76800    /* f32[128] */
#define OFF_B3  77312    /* f32[4]   */
#define LDS_BYTES 77328  /* <= 80KB -> 2 blocks/CU (was 82960 -> 1)      */

// Kahan-accurate 2x2 determinant (sign must match the f64 numpy reference's
// rotation-vs-reflection branch).
__device__ inline float kdet(float a, float b, float c, float d) {
    float w = b * c;
    float e = fmaf(b, c, -w);
    return fmaf(a, d, -w) - e;
}

// Orthogonal polar factor R of F=[[a,b],[c,d]] (== U@Vh of the SVD).
__device__ inline void polar2(float a, float b, float c, float d, float det,
                              float& R00, float& R01, float& R10, float& R11) {
    if (det >= 0.f) {
        float h1 = a + d, h2 = c - b;
        float q = fmaxf(sqrtf(h1 * h1 + h2 * h2), 1e-30f);
        float iq = 1.f / q;
        R00 = h1 * iq; R01 = -h2 * iq; R10 = h2 * iq; R11 = h1 * iq;
    } else {
        float h1 = a - d, h2 = b + c;
        float q = fmaxf(sqrtf(h1 * h1 + h2 * h2), 1e-30f);
        float iq = 1.f / q;
        R00 = h1 * iq; R01 = h2 * iq; R10 = h2 * iq; R11 = -h1 * iq;
    }
}

// Logical K-slot map used identically on A and B sides (permutation cancels
// inside MFMA): k(g,e) = 4g + (e&3) + 16*(e>>2).
// Hidden-channel map (absorbs C/D layout col=lane&15,row=4*(lane>>4)+reg):
// c(g,e,kb) = 32kb + 16*(e>>2) + 4g + (e&3).
__device__ inline void stage_weights(unsigned char* s, const float* w1, int D,
                                     const float* b1, const float* w2, const float* b2,
                                     const float* w3, const float* b3) {
    const int tid = threadIdx.x, nt = blockDim.x;
    for (int idx = tid; idx < 2048; idx += nt) {           // w2 hi+lo: (j,kb,g)
        int j = idx >> 4, kb = (idx >> 2) & 3, g = idx & 3;
        const float* src = w2 + j * 128 + kb * 32 + g * 4;
        f16x8 vh, vl;
        #pragma unroll
        for (int e = 0; e < 8; ++e) {
            float w = src[(e & 3) + 16 * (e >> 2)];
            _Float16 h = (_Float16)w;
            vh[e] = h;
            vl[e] = (_Float16)(w - (float)h);
        }
        int off = j * 256 + ((kb * 64 + g * 16) ^ ((j & 7) << 4));
        *(f16x8*)(s + OFF_W2H + off) = vh;
        *(f16x8*)(s + OFF_W2L + off) = vl;
    }
    // w1 packed split: logical k in [0,D): W_hi (pairs x_hi); [8,8+D): W_hi
    // (pairs x_lo); [16,16+D): W_lo (pairs x_hi). One MFMA does all 3 terms.
    for (int idx = tid; idx < 512; idx += nt) {            // (j,g)
        int j = idx >> 2, g = idx & 3;
        f16x8 v;
        #pragma unroll
        for (int e = 0; e < 8; ++e) {
            int k = 4 * g + (e & 3) + 16 * (e >> 2);
            _Float16 val = (_Float16)0.f;
            if (k < D) val = (_Float16)w1[j * D + k];
            else if (k >= 8 && k < 8 + D) val = (_Float16)w1[j * D + (k - 8)];
            else if (k >= 16 && k < 16 + D) {
                float w = w1[j * D + (k - 16)];
                val = (_Float16)(w - (float)(_Float16)w);
            }
            v[e] = val;
        }
        int gg = g ^ ((j ^ (j >> 2)) & 3);
        *(f16x8*)(s + OFF_W1 + j * 64 + gg * 16) = v;
    }
    // w3: 4 real rows + 1 shared zero row (MFMA rows 4..15 alias row 4).
    for (int idx = tid; idx < 80; idx += nt) {             // (j,kb,g), j in 0..4
        int j = idx >> 4, kb = (idx >> 2) & 3, g = idx & 3;
        f16x8 vh, vl;
        #pragma unroll
        for (int e = 0; e < 8; ++e) {
            int c = 32 * kb + 4 * g + (e & 3) + 16 * (e >> 2);
            float w = (j < 4) ? w3[j * 128 + c] : 0.f;
            _Float16 h = (_Float16)w;
            vh[e] = h;
            vl[e] = (_Float16)(w - (float)h);
        }
        int off = j * 256 + ((kb * 64 + g * 16) ^ ((j & 7) << 4));
        *(f16x8*)(s + OFF_W3H + off) = vh;
        *(f16x8*)(s + OFF_W3L + off) = vl;
    }
    for (int idx = tid; idx < 128; idx += nt) {
        ((float*)(s + OFF_B1))[idx] = b1[idx];
        ((float*)(s + OFF_B2))[idx] = b2[idx];
    }
    if (tid < 4) ((float*)(s + OFF_B3))[tid] = b3[tid];
}

// Build the layer-1 B fragment from x[0..7] (zero-padded past D).
// Per the packed-k map: g0:{xh0..3,xh0..3} g1:{xh4..7,xh4..7}
//                       g2:{xl0..3,0..}    g3:{xl4..7,0..}
__device__ inline f16x8 build_b1(const float* xin, int g) {
    _Float16 xh[8], xl[8];
    #pragma unroll
    for (int c = 0; c < 8; ++c) {
        float v = xin[c];
        _Float16 h = (_Float16)v;
        xh[c] = h;
        xl[c] = (_Float16)(v - (float)h);
    }
    const _Float16 z = (_Float16)0.f;
    f16x8 b;
    if (g == 0) {
        b[0] = xh[0]; b[1] = xh[1]; b[2] = xh[2]; b[3] = xh[3];
        b[4] = xh[0]; b[5] = xh[1]; b[6] = xh[2]; b[7] = xh[3];
    } else if (g == 1) {
        b[0] = xh[4]; b[1] = xh[5]; b[2] = xh[6]; b[3] = xh[7];
        b[4] = xh[4]; b[5] = xh[5]; b[6] = xh[6]; b[7] = xh[7];
    } else if (g == 2) {
        b[0] = xl[0]; b[1] = xl[1]; b[2] = xl[2]; b[3] = xl[3];
        b[4] = z; b[5] = z; b[6] = z; b[7] = z;
    } else {
        b[0] = xl[4]; b[1] = xl[5]; b[2] = xl[6]; b[3] = xl[7];
        b[4] = z; b[5] = z; b[6] = z; b[7] = z;
    }
    return b;
}

// Split-fp16 MLP, f32-quality: each logical GEMM = Wh*xh + Wh*xl + Wl*xh.
__device__ inline void mlp128(const unsigned char* s, f16x8 b1f, int m, int g,
                              float xout[4]) {
    const f32x4 zero = {0.f, 0.f, 0.f, 0.f};
    f32x4 acc[8];
    #pragma unroll
    for (int mb = 0; mb < 8; ++mb) {                       // layer1: 8 MFMAs
        int row = m + 16 * mb;
        int gg = g ^ ((row ^ (row >> 2)) & 3);
        f16x8 af = *(const f16x8*)(s + OFF_W1 + row * 64 + gg * 16);
        acc[mb] = __builtin_amdgcn_mfma_f32_16x16x32_f16(af, b1f, zero, 0, 0, 0);
    }
    #pragma unroll
    for (int mb = 0; mb < 8; ++mb) {                       // +b1, relu
        f32x4 bq = *(const f32x4*)(s + OFF_B1 + (mb * 16 + g * 4) * 4);
        #pragma unroll
        for (int r = 0; r < 4; ++r) acc[mb][r] = fmaxf(acc[mb][r] + bq[r], 0.f);
    }
    f16x8 hh[4], hl[4];
    #pragma unroll
    for (int kb = 0; kb < 4; ++kb)                         // split repack
        #pragma unroll
        for (int e = 0; e < 8; ++e) {
            float v = acc[2 * kb + (e >> 2)][e & 3];
            _Float16 h = (_Float16)v;
            hh[kb][e] = h;
            hl[kb][e] = (_Float16)(v - (float)h);
        }
    f32x4 acc2[8];
    #pragma unroll
    for (int mb = 0; mb < 8; ++mb) acc2[mb] = zero;
    #pragma unroll
    for (int mb = 0; mb < 8; ++mb) {                       // layer2: 96 MFMAs
        int row = m + 16 * mb;
        #pragma unroll
        for (int kb = 0; kb < 4; ++kb) {
            int off = row * 256 + ((kb * 64 + g * 16) ^ ((row & 7) << 4));
            f16x8 ah = *(const f16x8*)(s + OFF_W2H + off);
            f16x8 al = *(const f16x8*)(s + OFF_W2L + off);
            acc2[mb] = __builtin_amdgcn_mfma_f32_16x16x32_f16(ah, hh[kb], acc2[mb], 0, 0, 0);
            acc2[mb] = __builtin_amdgcn_mfma_f32_16x16x32_f16(ah, hl[kb], acc2[mb], 0, 0, 0);
            acc2[mb] = __builtin_amdgcn_mfma_f32_16x16x32_f16(al, hh[kb], acc2[mb], 0, 0, 0);
        }
    }
    #pragma unroll
    for (int mb = 0; mb < 8; ++mb) {                       // +b2, relu
        f32x4 bq = *(const f32x4*)(s + OFF_B2 + (mb * 16 + g * 4) * 4);
        #pragma unroll
        for (int r = 0; r < 4; ++r) acc2[mb][r] = fmaxf(acc2[mb][r] + bq[r], 0.f);
    }
    f16x8 h2h[4], h2l[4];
    #pragma unroll
    for (int kb = 0; kb < 4; ++kb)
        #pragma unroll
        for (int e = 0; e < 8; ++e) {
            float v = acc2[2 * kb + (e >> 2)][e & 3];
            _Float16 h = (_Float16)v;
            h2h[kb][e] = h;
            h2l[kb][e] = (_Float16)(v - (float)h);
        }
    f32x4 acc3 = zero;
    const int r3 = (m < 4) ? m : 4;                        // rows>=4 alias zero row
    #pragma unroll
    for (int kb = 0; kb < 4; ++kb) {                       // layer3: 12 MFMAs
        int off = r3 * 256 + ((kb * 64 + g * 16) ^ ((r3 & 7) << 4));
        f16x8 ah = *(const f16x8*)(s + OFF_W3H + off);
        f16x8 al = *(const f16x8*)(s + OFF_W3L + off);
        acc3 = __builtin_amdgcn_mfma_f32_16x16x32_f16(ah, h2h[kb], acc3, 0, 0, 0);
        acc3 = __builtin_amdgcn_mfma_f32_16x16x32_f16(ah, h2l[kb], acc3, 0, 0, 0);
        acc3 = __builtin_amdgcn_mfma_f32_16x16x32_f16(al, h2h[kb], acc3, 0, 0, 0);
    }
    f32x4 b3q = *(const f32x4*)(s + OFF_B3);
    #pragma unroll
    for (int o = 0; o < 4; ++o)                            // broadcast from g==0
        xout[o] = __shfl(acc3[o] + b3q[o], m, 64);
}

__global__ __launch_bounds__(512) void k_dc(const float* __restrict__ Fin,
    const float* __restrict__ w1, const float* __restrict__ b1,
    const float* __restrict__ w2, const float* __restrict__ b2,
    const float* __restrict__ w3, const float* __restrict__ b3,
    float* __restrict__ out, int nelem) {
    extern __shared__ unsigned char s[];
    stage_weights(s, w1, 7, b1, w2, b2, w3, b3);
    __syncthreads();
    const int lane = threadIdx.x & 63;
    const int m = lane & 15, g = lane >> 4;
    const int wid = blockIdx.x * (blockDim.x >> 6) + (threadIdx.x >> 6);
    const int nw = gridDim.x * (blockDim.x >> 6);
    const int niter = nelem >> 4;
    for (int it = wid; it < niter; it += nw) {
        const int elem = it * 16 + m;
        f32x4 f = ((const f32x4*)Fin)[elem];
        float a = f[0], b = f[1], c = f[2], d = f[3];
        float det = kdet(a, b, c, d);
        float R00, R01, R10, R11;
        polar2(a, b, c, d, det, R00, R01, R10, R11);
        float E = 0.5f * (a + d), Hh = 0.5f * (c - b);
        float Fv = 0.5f * (a - d), G = 0.5f * (b + c);
        float Q = sqrtf(E * E + Hh * Hh), Rr = sqrtf(Fv * Fv + G * G);
        float inv[8];
        inv[0] = Q + Rr - 1.f;                  // s1 - 1
        inv[1] = fabsf(Q - Rr) - 1.f;           // s2 - 1
        inv[2] = fmaf(a, a, c * c) - 1.f;       // F^T F - I
        inv[3] = fmaf(a, b, c * d);
        inv[4] = inv[3];
        inv[5] = fmaf(b, b, d * d) - 1.f;
        inv[6] = det - 1.f;
        inv[7] = 0.f;
        f16x8 b1f = build_b1(inv, g);
        float x[4];
        mlp128(s, b1f, m, g, x);
        float x01 = 0.5f * (x[1] + x[2]);       // symmetrize
        float Fp00 = fmaf(R00, x[0], fmaf(R01, x01, a));
        float Fp01 = fmaf(R00, x01, fmaf(R01, x[3], b));
        float Fp10 = fmaf(R10, x[0], fmaf(R11, x01, c));
        float Fp11 = fmaf(R10, x01, fmaf(R11, x[3], d));
        if (g == 0) {
            f32x4 r = {Fp00, Fp01, Fp10, Fp11};
            ((f32x4*)out)[elem] = r;            // stage Fp in d_out
        }
    }
}

__global__ __launch_bounds__(512) void k_sp(float* io,
    const float* __restrict__ w1, const float* __restrict__ b1,
    const float* __restrict__ w2, const float* __restrict__ b2,
    const float* __restrict__ w3, const float* __restrict__ b3, int nelem) {
    extern __shared__ unsigned char s[];
    stage_weights(s, w1, 3, b1, w2, b2, w3, b3);
    __syncthreads();
    const int lane = threadIdx.x & 63;
    const int m = lane & 15, g = lane >> 4;
    const int wid = blockIdx.x * (blockDim.x >> 6) + (threadIdx.x >> 6);
    const int nw = gridDim.x * (blockDim.x >> 6);
    const int niter = nelem >> 4;
    for (int it = wid; it < niter; it += nw) {
        const int elem = it * 16 + m;
        f32x4 fp = ((const f32x4*)io)[elem];    // Fp from k_dc
        float a = fp[0], b = fp[1], c = fp[2], d = fp[3];
        float det = kdet(a, b, c, d);
        float R00, R01, R10, R11;
        polar2(a, b, c, d, det, R00, R01, R10, R11);
        float E = 0.5f * (a + d), Hh = 0.5f * (c - b);
        float Fv = 0.5f * (a - d), G = 0.5f * (b + c);
        float Q = sqrtf(E * E + Hh * Hh), Rr = sqrtf(Fv * Fv + G * G);
        float inv[8];
        inv[0] = (Q + Rr) + fabsf(Q - Rr) - 2.f; // s1+s2-2
        inv[1] = fmaf(a, a, fmaf(b, b, fmaf(c, c, d * d))) - 1.f;
        inv[2] = det - 1.f;
        inv[3] = 0.f; inv[4] = 0.f; inv[5] = 0.f; inv[6] = 0.f; inv[7] = 0.f;
        f16x8 b1f = build_b1(inv, g);
        float y[4];
        mlp128(s, b1f, m, g, y);
        float y01 = 0.5f * (y[1] + y[2]);
        float P00 = fmaf(R00, y[0], R01 * y01);
        float P01 = fmaf(R00, y01, R01 * y[3]);
        float P10 = fmaf(R10, y[0], R11 * y01);
        float P11 = fmaf(R10, y01, R11 * y[3]);
        // cauchy = P @ Fp^T
        float C00 = fmaf(P00, a, P01 * b);
        float C01 = fmaf(P00, c, P01 * d);
        float C10 = fmaf(P10, a, P11 * b);
        float C11 = fmaf(P10, c, P11 * d);
        if (g == 0) {
            f32x4 r = {C00, C01, C10, C11};
            ((f32x4*)io)[elem] = r;
        }
    }
}

extern "C" void kernel_launch(void* const* d_in, const int* in_sizes, int n_in,
                              void* d_out, int out_size, void* d_ws, size_t ws_size,
                              hipStream_t stream) {
    const float* F     = (const float*)d_in[0];
    const float* dc_w1 = (const float*)d_in[1];
    const float* dc_b1 = (const float*)d_in[2];
    const float* dc_w2 = (const float*)d_in[3];
    const float* dc_b2 = (const float*)d_in[4];
    const float* dc_w3 = (const float*)d_in[5];
    const float* dc_b3 = (const float*)d_in[6];
    const float* sp_w1 = (const float*)d_in[7];
    const float* sp_b1 = (const float*)d_in[8];
    const float* sp_w2 = (const float*)d_in[9];
    const float* sp_b2 = (const float*)d_in[10];
    const float* sp_w3 = (const float*)d_in[11];
    const float* sp_b3 = (const float*)d_in[12];
    float* out = (float*)d_out;
    const int nelem = in_sizes[0] / 4;
    // >64KB dynamic LDS opt-in (host-side attr set; not a stream op, so
    // graph-capture-safe; idempotent).
    hipFuncSetAttribute((const void*)k_dc,
                        hipFuncAttributeMaxDynamicSharedMemorySize, LDS_BYTES);
    hipFuncSetAttribute((const void*)k_sp,
                        hipFuncAttributeMaxDynamicSharedMemorySize, LDS_BYTES);
    dim3 grid(512), block(512);                 // 2 blocks/CU (LDS 77.3KB)
    k_dc<<<grid, block, LDS_BYTES, stream>>>(F, dc_w1, dc_b1, dc_w2, dc_b2,
                                             dc_w3, dc_b3, out, nelem);
    k_sp<<<grid, block, LDS_BYTES, stream>>>(out, sp_w1, sp_b1, sp_w2, sp_b2,
                                             sp_w3, sp_b3, nelem);
}